// Round 3
// baseline (260.734 us; speedup 1.0000x reference)
//
#include <hip/hip_runtime.h>
#include <math.h>

#define NATOMS 4096
#define R_CUT 5.0f
#define BLOCK 256
#define F4_PER_ROW (NATOMS / 4)          // 1024 float4 per mask row
#define F4_PER_THREAD (F4_PER_ROW / BLOCK) // 4

// Wave-uniform binary searches over the sorted batch array.
__device__ __forceinline__ int lower_bound_i(const int* __restrict__ b, int n, int v) {
    int lo = 0, hi = n;
    while (lo < hi) { int mid = (lo + hi) >> 1; if (b[mid] < v) lo = mid + 1; else hi = mid; }
    return lo;
}
__device__ __forceinline__ int upper_bound_i(const int* __restrict__ b, int n, int v) {
    int lo = 0, hi = n;
    while (lo < hi) { int mid = (lo + hi) >> 1; if (b[mid] <= v) lo = mid + 1; else hi = mid; }
    return lo;
}

// One block per row i. Writes the full mask row densely (coalesced float4),
// computes pairs only inside the same-graph index range [g0,g1) (batch is
// sorted), scatter-writes disp for true edges. Off-range / non-edge disp
// entries are zeroed by the hipMemsetAsync issued before this kernel.
__global__ __launch_bounds__(BLOCK) void radius_graph_sparse_kernel(
    const float* __restrict__ pos,    // [N,3]
    const float* __restrict__ cell,   // [B,3,3]
    const int*   __restrict__ batch,  // [N]
    float* __restrict__ disp_out,     // [N,N,3] (pre-zeroed)
    float* __restrict__ mask_out)     // [N,N] as 0/1 float
{
    const int i   = blockIdx.x;
    const int tid = (int)threadIdx.x;

    // Wave-uniform row data (scalar-unit friendly).
    const int bi = batch[i];
    const float pix = pos[i * 3 + 0];
    const float piy = pos[i * 3 + 1];
    const float piz = pos[i * 3 + 2];

    const float* C = cell + bi * 9;
    const float C00 = C[0], C01 = C[1], C02 = C[2];
    const float C10 = C[3], C11 = C[4], C12 = C[5];
    const float C20 = C[6], C21 = C[7], C22 = C[8];
    // A = inv(C^T) = cofactor(C) / det(C)
    const float cof00 =  (C11 * C22 - C12 * C21);
    const float cof01 = -(C10 * C22 - C12 * C20);
    const float cof02 =  (C10 * C21 - C11 * C20);
    const float cof10 = -(C01 * C22 - C02 * C21);
    const float cof11 =  (C00 * C22 - C02 * C20);
    const float cof12 = -(C00 * C21 - C01 * C20);
    const float cof20 =  (C01 * C12 - C02 * C11);
    const float cof21 = -(C00 * C12 - C02 * C10);
    const float cof22 =  (C00 * C11 - C01 * C10);
    const float det = C00 * cof00 + C01 * cof01 + C02 * cof02;
    const float id  = 1.0f / det;
    const float A00 = cof00 * id, A01 = cof01 * id, A02 = cof02 * id;
    const float A10 = cof10 * id, A11 = cof11 * id, A12 = cof12 * id;
    const float A20 = cof20 * id, A21 = cof21 * id, A22 = cof22 * id;

    // Same-graph column range (batch sorted): j in [g0,g1) <=> batch[j]==bi.
    const int g0 = lower_bound_i(batch, NATOMS, bi);
    const int g1 = upper_bound_i(batch, NATOMS, bi);

    float* __restrict__ drow = disp_out + (size_t)i * (NATOMS * 3);
    float4* __restrict__ mrow = (float4*)(mask_out + (size_t)i * NATOMS);

    #pragma unroll
    for (int s = 0; s < F4_PER_THREAD; ++s) {
        const int f4 = tid + s * BLOCK;     // float4 index within the row
        const int jbase = f4 * 4;
        float4 mv = make_float4(0.0f, 0.0f, 0.0f, 0.0f);

        if (jbase + 3 >= g0 && jbase < g1) {
            float* mvp = (float*)&mv;
            #pragma unroll
            for (int e = 0; e < 4; ++e) {
                const int j = jbase + e;
                if (j >= g0 && j < g1 && j != i) {
                    // raw displacement, exact-order f32 (matches numpy)
                    const float d0 = __fsub_rn(pix, pos[j * 3 + 0]);
                    const float d1 = __fsub_rn(piy, pos[j * 3 + 1]);
                    const float d2 = __fsub_rn(piz, pos[j * 3 + 2]);

                    const float s0 = __fadd_rn(__fadd_rn(__fmul_rn(A00, d0), __fmul_rn(A01, d1)), __fmul_rn(A02, d2));
                    const float s1 = __fadd_rn(__fadd_rn(__fmul_rn(A10, d0), __fmul_rn(A11, d1)), __fmul_rn(A12, d2));
                    const float s2 = __fadd_rn(__fadd_rn(__fmul_rn(A20, d0), __fmul_rn(A21, d1)), __fmul_rn(A22, d2));

                    const float r0 = rintf(s0);   // round-half-even == jnp.round
                    const float r1 = rintf(s1);
                    const float r2 = rintf(s2);

                    const float w0 = __fsub_rn(d0, __fadd_rn(__fadd_rn(__fmul_rn(C00, r0), __fmul_rn(C01, r1)), __fmul_rn(C02, r2)));
                    const float w1 = __fsub_rn(d1, __fadd_rn(__fadd_rn(__fmul_rn(C10, r0), __fmul_rn(C11, r1)), __fmul_rn(C12, r2)));
                    const float w2 = __fsub_rn(d2, __fadd_rn(__fadd_rn(__fmul_rn(C20, r0), __fmul_rn(C21, r1)), __fmul_rn(C22, r2)));

                    const float n2 = __fadd_rn(__fadd_rn(__fmul_rn(w0, w0), __fmul_rn(w1, w1)), __fmul_rn(w2, w2));
                    if (sqrtf(n2) < R_CUT) {
                        mvp[e] = 1.0f;
                        drow[j * 3 + 0] = w0;
                        drow[j * 3 + 1] = w1;
                        drow[j * 3 + 2] = w2;
                    }
                }
            }
        }
        mrow[f4] = mv;   // dense, coalesced mask store
    }
}

extern "C" void kernel_launch(void* const* d_in, const int* in_sizes, int n_in,
                              void* d_out, int out_size, void* d_ws, size_t ws_size,
                              hipStream_t stream) {
    const float* pos   = (const float*)d_in[0];
    const float* cell  = (const float*)d_in[1];
    const int*   batch = (const int*)d_in[2];

    float* disp_out = (float*)d_out;
    float* mask_out = (float*)d_out + (size_t)NATOMS * NATOMS * 3;

    // Zero the disp region at memset fill rate (~6.6 TB/s measured on this
    // harness); the kernel only scatter-writes true edges on top.
    hipMemsetAsync(disp_out, 0, (size_t)NATOMS * NATOMS * 3 * sizeof(float), stream);

    radius_graph_sparse_kernel<<<NATOMS, BLOCK, 0, stream>>>(
        pos, cell, batch, disp_out, mask_out);
}